// Round 6
// baseline (47.445 us; speedup 1.0000x reference)
//
#include <hip/hip_runtime.h>
#include <hip/hip_bf16.h>
#include <math.h>

#define NUM_ITEMS 10000
#define EMBED_DIM 64
#define MAX_HIST 200
#define NPAD 208          // MAX_HIST padded to multiple of 16
#define BATCH 32
#define LEAKY 0.2f
#define W_USER 0.5f
#define LOG2E 1.4426950408889634f
#define ECLAMP 110.0f     // exp2 ceiling: Sh <= 208*2^110*2^6*4 ~ 2^126 < FLT_MAX

typedef short bf16x8 __attribute__((ext_vector_type(8)));
typedef float f32x4 __attribute__((ext_vector_type(4)));

__device__ __forceinline__ unsigned short f2bf(float f) {
    __hip_bfloat16 h = __float2bfloat16(f);
    return __builtin_bit_cast(unsigned short, h);
}

__device__ __forceinline__ float fexp2(float x) {
#if __has_builtin(__builtin_amdgcn_exp2f)
    return __builtin_amdgcn_exp2f(x);
#else
    return exp2f(x);
#endif
}

// ---------------- Kernel P (fused prep):
// blocks [0, NUM_ITEMS/4):      wti_bf = bf16(items@W), items_att_bf = bf16(items*log2e), bdot
// blocks [NUM_ITEMS/4, +BATCH): hist gather -> bf16 (NPAD rows), user softmax -> uh_bf[b][64]
__global__ __launch_bounds__(256) void prep_kernel(const int* __restrict__ ids,
                                                   const int* __restrict__ lens,
                                                   const float* __restrict__ items,
                                                   const float* __restrict__ user,
                                                   const float* __restrict__ W,
                                                   const float* __restrict__ bias,
                                                   unsigned short* __restrict__ items_att_bf,
                                                   unsigned short* __restrict__ wti_bf,
                                                   float* __restrict__ bdot,
                                                   unsigned short* __restrict__ hist_bf,
                                                   unsigned short* __restrict__ uh_bf) {
    const int tid = threadIdx.x;
    __shared__ float shW[EMBED_DIM * EMBED_DIM];  // 16 KB (wti part only)
    __shared__ float red[8];
    __shared__ float sh_usf[NPAD];
    __shared__ float sh_uh[4][EMBED_DIM];

    if (blockIdx.x < NUM_ITEMS / 4) {
        // ---- WtI part ----
        for (int idx = tid; idx < EMBED_DIM * EMBED_DIM; idx += 256) shW[idx] = W[idx];
        __syncthreads();

        const int i = blockIdx.x * 4 + (tid >> 6);
        const int g = tid & 63;
        const float* irow = items + i * EMBED_DIM;

        float acc = 0.f;
#pragma unroll
        for (int f = 0; f < EMBED_DIM; ++f) acc += irow[f] * shW[f * EMBED_DIM + g];

        wti_bf[i * EMBED_DIM + g] = f2bf(acc);
        // pre-scale attention operand by log2(e): leaky is positively homogeneous,
        // so exp2(log2e * leaky(s)) == exp(leaky(s)) exactly
        items_att_bf[i * EMBED_DIM + g] = f2bf(irow[g] * LOG2E);

        float bv = bias[g] * irow[g];
#pragma unroll
        for (int o = 32; o > 0; o >>= 1) bv += __shfl_xor(bv, o, 64);
        if (g == 0) bdot[i] = bv;
    } else {
        // ---- hist gather + user softmax + uh part ----
        const int b = blockIdx.x - NUM_ITEMS / 4;

        for (int idx = tid; idx < NPAD * 8; idx += 256) {
            const int n = idx >> 3, q = idx & 7;
            bf16x8 v = (bf16x8)0;
            if (n < MAX_HIST) {
                const int id = ids[b * MAX_HIST + n];
                const float4* p = (const float4*)(items + id * EMBED_DIM + q * 8);
                float4 v0 = p[0], v1 = p[1];
                v[0] = (short)f2bf(v0.x); v[1] = (short)f2bf(v0.y);
                v[2] = (short)f2bf(v0.z); v[3] = (short)f2bf(v0.w);
                v[4] = (short)f2bf(v1.x); v[5] = (short)f2bf(v1.y);
                v[6] = (short)f2bf(v1.z); v[7] = (short)f2bf(v1.w);
            }
            *(bf16x8*)(hist_bf + (size_t)(b * NPAD + n) * EMBED_DIM + q * 8) = v;
        }

        const int len = lens[b];
        float s = -INFINITY;
        if (tid < len) {
            const int id = ids[b * MAX_HIST + tid];
            const float* h = items + id * EMBED_DIM;
            float a0 = 0.f, a1 = 0.f;
#pragma unroll
            for (int f = 0; f < EMBED_DIM; f += 2) {
                a0 += user[f] * h[f];
                a1 += user[f + 1] * h[f + 1];
            }
            float a = a0 + a1;
            s = fmaxf(a, LEAKY * a);
        }
        float m = s;
#pragma unroll
        for (int o = 32; o > 0; o >>= 1) m = fmaxf(m, __shfl_xor(m, o, 64));
        if ((tid & 63) == 0) red[tid >> 6] = m;
        __syncthreads();
        m = fmaxf(fmaxf(red[0], red[1]), fmaxf(red[2], red[3]));

        float e = (tid < len) ? __expf(s - m) : 0.f;
        float t = e;
#pragma unroll
        for (int o = 32; o > 0; o >>= 1) t += __shfl_xor(t, o, 64);
        if ((tid & 63) == 0) red[4 + (tid >> 6)] = t;
        __syncthreads();
        const float sum = red[4] + red[5] + red[6] + red[7];

        if (tid < NPAD) sh_usf[tid] = (tid < len) ? (e / sum) : 0.f;
        __syncthreads();

        // uh[f] = sum_n us[n] * items[ids[n]][f]   (fp32 accumulate, bf16 store)
        const int f = tid & 63;
        const int part = tid >> 6;
        float uhp = 0.f;
        for (int n = part; n < len; n += 4)
            uhp += sh_usf[n] * items[(size_t)ids[b * MAX_HIST + n] * EMBED_DIM + f];
        sh_uh[part][f] = uhp;
        __syncthreads();
        if (tid < EMBED_DIM)
            uh_bf[b * EMBED_DIM + tid] =
                f2bf(sh_uh[0][tid] + sh_uh[1][tid] + sh_uh[2][tid] + sh_uh[3][tid]);
    }
}

// ---------------- Kernel C: MFMA main — 2 item-groups per wave (32 items), LDS prefetch
__global__ __launch_bounds__(256) void main_kernel(const unsigned short* __restrict__ items_att_bf,
                                                   const unsigned short* __restrict__ wti_bf,
                                                   const float* __restrict__ bdot,
                                                   const unsigned short* __restrict__ hist_bf,
                                                   const unsigned short* __restrict__ uh_bf,
                                                   const int* __restrict__ lens,
                                                   float* __restrict__ out) {
    const int b = blockIdx.y;
    const int tid = threadIdx.x;
    const int lane = tid & 63;
    const int w = tid >> 6;

    __shared__ __align__(16) unsigned short sh_hist[NPAD * EMBED_DIM];  // 26.6 KB, swizzled

    const int len = lens[b];                 // block-uniform
    const int ntiles = (len + 15) >> 4;      // 1..13

    const int c16 = lane & 15;   // item column within 16-group
    const int g = lane >> 4;     // k-chunk / n-subrow group
    const int i0 = blockIdx.x * 128 + w * 32;
    const int iA = i0 + c16;
    const int iB = i0 + 16 + c16;

    // B-fragment global loads issued FIRST: latency hides under staging + barrier.
    // Tail reads (i >= NUM_ITEMS) land in adjacent ws regions (allocated, garbage ok;
    // groups keep private accumulators and stores are guarded).
    bf16x8 itfA0 = *(const bf16x8*)(items_att_bf + (size_t)iA * 64 + g * 8);
    bf16x8 itfA1 = *(const bf16x8*)(items_att_bf + (size_t)iA * 64 + 32 + g * 8);
    bf16x8 wtfA0 = *(const bf16x8*)(wti_bf + (size_t)iA * 64 + g * 8);
    bf16x8 wtfA1 = *(const bf16x8*)(wti_bf + (size_t)iA * 64 + 32 + g * 8);
    bf16x8 itfB0 = *(const bf16x8*)(items_att_bf + (size_t)iB * 64 + g * 8);
    bf16x8 itfB1 = *(const bf16x8*)(items_att_bf + (size_t)iB * 64 + 32 + g * 8);
    bf16x8 wtfB0 = *(const bf16x8*)(wti_bf + (size_t)iB * 64 + g * 8);
    bf16x8 wtfB1 = *(const bf16x8*)(wti_bf + (size_t)iB * 64 + 32 + g * 8);
    bf16x8 u0 = *(const bf16x8*)(uh_bf + b * 64 + g * 8);
    bf16x8 u1 = *(const bf16x8*)(uh_bf + b * 64 + 32 + g * 8);

    // stage only the rows we need (XOR-swizzle: row stride 128 B)
    const float4* src = (const float4*)(hist_bf + (size_t)b * NPAD * EMBED_DIM);
    const int nf4 = ntiles * 16 * 8;
    for (int c = tid; c < nf4; c += 256) {
        const int n = c >> 3, q = c & 7;
        float4 v = src[c];
        const int byte = (n * 128 + q * 16) ^ ((n & 7) << 4);
        *(float4*)((char*)sh_hist + byte) = v;
    }
    __syncthreads();

    if (i0 >= NUM_ITEMS) return;   // whole wave dead (post-barrier: staging done)

    // user-perspective term via broadcast-A MFMA: Su = uh[b] . wti[i]
    f32x4 sufA = (f32x4)0.f, sufB = (f32x4)0.f;
    sufA = __builtin_amdgcn_mfma_f32_16x16x32_bf16(u0, wtfA0, sufA, 0, 0, 0);
    sufA = __builtin_amdgcn_mfma_f32_16x16x32_bf16(u1, wtfA1, sufA, 0, 0, 0);
    sufB = __builtin_amdgcn_mfma_f32_16x16x32_bf16(u0, wtfB0, sufB, 0, 0, 0);
    sufB = __builtin_amdgcn_mfma_f32_16x16x32_bf16(u1, wtfB1, sufB, 0, 0, 0);
    const float SuA = sufA[0];
    const float SuB = sufB[0];

    float SeA = 0.f, ShA = 0.f, SeB = 0.f, ShB = 0.f;

    const char* hbase = (const char*)sh_hist;
#define LDA(T, X0, X1)                                                   \
    {                                                                    \
        const int n_ = (T) * 16 + c16;                                   \
        const int base_ = n_ * 128, sw_ = (n_ & 7) << 4;                 \
        X0 = *(const bf16x8*)(hbase + ((base_ + g * 16) ^ sw_));         \
        X1 = *(const bf16x8*)(hbase + ((base_ + 64 + g * 16) ^ sw_));    \
    }

#define EPI(S, H, Se, Sh, MASKED, NB)                                    \
    {                                                                    \
        float s0 = fminf(fmaxf(S[0], LEAKY * S[0]), ECLAMP);             \
        float s1 = fminf(fmaxf(S[1], LEAKY * S[1]), ECLAMP);             \
        float s2 = fminf(fmaxf(S[2], LEAKY * S[2]), ECLAMP);             \
        float s3 = fminf(fmaxf(S[3], LEAKY * S[3]), ECLAMP);             \
        if (MASKED) {                                                    \
            s0 = ((NB) + 0 < len) ? s0 : -INFINITY;                      \
            s1 = ((NB) + 1 < len) ? s1 : -INFINITY;                      \
            s2 = ((NB) + 2 < len) ? s2 : -INFINITY;                      \
            s3 = ((NB) + 3 < len) ? s3 : -INFINITY;                      \
        }                                                                \
        const float e0 = fexp2(s0), e1 = fexp2(s1);                      \
        const float e2 = fexp2(s2), e3 = fexp2(s3);                      \
        Se += (e0 + e1) + (e2 + e3);                                     \
        Sh = fmaf(e0, H[0], fmaf(e1, H[1], fmaf(e2, H[2], fmaf(e3, H[3], Sh)))); \
    }

#define MFMA8(A0, A1, SA, HA, SB, HB)                                     \
    SA = __builtin_amdgcn_mfma_f32_16x16x32_bf16(A0, itfA0, SA, 0, 0, 0); \
    SA = __builtin_amdgcn_mfma_f32_16x16x32_bf16(A1, itfA1, SA, 0, 0, 0); \
    SB = __builtin_amdgcn_mfma_f32_16x16x32_bf16(A0, itfB0, SB, 0, 0, 0); \
    SB = __builtin_amdgcn_mfma_f32_16x16x32_bf16(A1, itfB1, SB, 0, 0, 0); \
    HA = __builtin_amdgcn_mfma_f32_16x16x32_bf16(A0, wtfA0, HA, 0, 0, 0); \
    HA = __builtin_amdgcn_mfma_f32_16x16x32_bf16(A1, wtfA1, HA, 0, 0, 0); \
    HB = __builtin_amdgcn_mfma_f32_16x16x32_bf16(A0, wtfB0, HB, 0, 0, 0); \
    HB = __builtin_amdgcn_mfma_f32_16x16x32_bf16(A1, wtfB1, HB, 0, 0, 0);

    bf16x8 a0, a1;
    LDA(0, a0, a1)

    for (int t = 0; t < ntiles - 1; ++t) {
        f32x4 SA = (f32x4)0.f, HA = (f32x4)0.f, SB = (f32x4)0.f, HB = (f32x4)0.f;
        MFMA8(a0, a1, SA, HA, SB, HB)
        bf16x8 p0, p1;
        LDA(t + 1, p0, p1)                       // prefetch next tile (t+1 <= ntiles-1: in range)
        const int nb = t * 16 + g * 4;
        (void)nb;
        EPI(SA, HA, SeA, ShA, 0, 0)
        EPI(SB, HB, SeB, ShB, 0, 0)
        a0 = p0; a1 = p1;
    }
    {   // final tile, masked
        f32x4 SA = (f32x4)0.f, HA = (f32x4)0.f, SB = (f32x4)0.f, HB = (f32x4)0.f;
        MFMA8(a0, a1, SA, HA, SB, HB)
        const int nb = (ntiles - 1) * 16 + g * 4;
        EPI(SA, HA, SeA, ShA, 1, nb)
        EPI(SB, HB, SeB, ShB, 1, nb)
    }
#undef MFMA8
#undef EPI
#undef LDA

    // fixed-scale combine across the 4 n-groups; clamp bounds Sh ~ 2^126 < FLT_MAX
    SeA += __shfl_xor(SeA, 16, 64); SeA += __shfl_xor(SeA, 32, 64);
    ShA += __shfl_xor(ShA, 16, 64); ShA += __shfl_xor(ShA, 32, 64);
    SeB += __shfl_xor(SeB, 16, 64); SeB += __shfl_xor(SeB, 32, 64);
    ShB += __shfl_xor(ShB, 16, 64); ShB += __shfl_xor(ShB, 32, 64);

    if (g == 0) {
        if (iA < NUM_ITEMS)
            out[(size_t)b * NUM_ITEMS + iA] =
                (1.0f - W_USER) * (ShA / SeA) + W_USER * SuA + bdot[iA];
        if (iB < NUM_ITEMS)
            out[(size_t)b * NUM_ITEMS + iB] =
                (1.0f - W_USER) * (ShB / SeB) + W_USER * SuB + bdot[iB];
    }
}

extern "C" void kernel_launch(void* const* d_in, const int* in_sizes, int n_in,
                              void* d_out, int out_size, void* d_ws, size_t ws_size,
                              hipStream_t stream) {
    const int* ids = (const int*)d_in[0];
    const int* lens = (const int*)d_in[1];
    const float* items = (const float*)d_in[2];
    const float* user = (const float*)d_in[3];
    const float* W = (const float*)d_in[4];
    const float* bias = (const float*)d_in[5];
    float* out = (float*)d_out;

    char* p = (char*)d_ws;
    unsigned short* items_att_bf = (unsigned short*)p; p += (size_t)NUM_ITEMS * EMBED_DIM * 2;
    unsigned short* wti_bf       = (unsigned short*)p; p += (size_t)NUM_ITEMS * EMBED_DIM * 2;
    float* bdot                  = (float*)p;          p += (size_t)NUM_ITEMS * 4;
    unsigned short* hist_bf      = (unsigned short*)p; p += (size_t)BATCH * NPAD * EMBED_DIM * 2;
    unsigned short* uh_bf        = (unsigned short*)p; p += (size_t)BATCH * EMBED_DIM * 2;

    prep_kernel<<<NUM_ITEMS / 4 + BATCH, 256, 0, stream>>>(ids, lens, items, user, W, bias,
                                                           items_att_bf, wti_bf, bdot,
                                                           hist_bf, uh_bf);

    dim3 grid((NUM_ITEMS + 127) / 128, BATCH);
    main_kernel<<<grid, 256, 0, stream>>>(items_att_bf, wti_bf, bdot, hist_bf, uh_bf, lens, out);
}

// Round 7
// 44.577 us; speedup vs baseline: 1.0643x; 1.0643x over previous
//
#include <hip/hip_runtime.h>
#include <hip/hip_bf16.h>
#include <math.h>

#define NUM_ITEMS 10000
#define EMBED_DIM 64
#define MAX_HIST 200
#define NPAD 208          // MAX_HIST padded to multiple of 16
#define BATCH 32
#define LEAKY 0.2f
#define W_USER 0.5f
#define LOG2E 1.4426950408889634f
#define ECLAMP 110.0f     // exp2 ceiling: Sh <= 208*2^110*2^6*4 ~ 2^126 < FLT_MAX
#define NWTI 157          // ceil(10000/64) blocks for the wti part of prep

typedef short bf16x8 __attribute__((ext_vector_type(8)));
typedef float f32x4 __attribute__((ext_vector_type(4)));

__device__ __forceinline__ unsigned short f2bf(float f) {
    __hip_bfloat16 h = __float2bfloat16(f);
    return __builtin_bit_cast(unsigned short, h);
}

__device__ __forceinline__ float bf2f(unsigned short u) {
    return __builtin_bit_cast(float, (unsigned int)u << 16);
}

__device__ __forceinline__ float fexp2(float x) {
#if __has_builtin(__builtin_amdgcn_exp2f)
    return __builtin_amdgcn_exp2f(x);
#else
    return exp2f(x);
#endif
}

// ---------------- Kernel P (fused prep):
// blocks [0, NWTI):        wti_bf = bf16(items@W), items_att_bf = bf16(items*log2e), bdot
// blocks [NWTI, NWTI+32):  hist gather -> bf16 (NPAD rows), user softmax -> uh_bf[b][64]
__global__ __launch_bounds__(256) void prep_kernel(const int* __restrict__ ids,
                                                   const int* __restrict__ lens,
                                                   const float* __restrict__ items,
                                                   const float* __restrict__ user,
                                                   const float* __restrict__ W,
                                                   const float* __restrict__ bias,
                                                   unsigned short* __restrict__ items_att_bf,
                                                   unsigned short* __restrict__ wti_bf,
                                                   float* __restrict__ bdot,
                                                   unsigned short* __restrict__ hist_bf,
                                                   unsigned short* __restrict__ uh_bf) {
    const int tid = threadIdx.x;
    // overlay: wti branch uses it as float shW[4096] (16 KB);
    //          hist branch uses it as bf16 sh_h[NPAD*64] (26 KB)
    __shared__ __align__(16) char sbuf[NPAD * EMBED_DIM * 2];
    __shared__ float red[8];
    __shared__ float sh_usf[NPAD];
    __shared__ float sh_uh[4][EMBED_DIM];

    if (blockIdx.x < NWTI) {
        // ---- WtI part: 64 items per block ----
        float* shW = (float*)sbuf;
        for (int idx = tid; idx < EMBED_DIM * EMBED_DIM; idx += 256) shW[idx] = W[idx];
        __syncthreads();

        const int g = tid & 63;
        const int isub = tid >> 6;
        const int base = blockIdx.x * 64 + isub * 16;

        for (int k = 0; k < 16; ++k) {
            const int i = base + k;
            if (i >= NUM_ITEMS) break;
            const float* irow = items + (size_t)i * EMBED_DIM;

            float acc = 0.f;
#pragma unroll
            for (int f = 0; f < EMBED_DIM; ++f) acc += irow[f] * shW[f * EMBED_DIM + g];

            wti_bf[i * EMBED_DIM + g] = f2bf(acc);
            // pre-scale attention operand by log2(e): leaky is positively homogeneous,
            // so exp2(log2e * leaky(s)) == exp(leaky(s)) exactly
            items_att_bf[i * EMBED_DIM + g] = f2bf(irow[g] * LOG2E);

            float bv = bias[g] * irow[g];
#pragma unroll
            for (int o = 32; o > 0; o >>= 1) bv += __shfl_xor(bv, o, 64);
            if (g == 0) bdot[i] = bv;
        }
    } else {
        // ---- hist gather + user softmax + uh part ----
        const int b = blockIdx.x - NWTI;
        unsigned short* sh_h = (unsigned short*)sbuf;  // [NPAD][64] bf16, linear

        for (int idx = tid; idx < NPAD * 8; idx += 256) {
            const int n = idx >> 3, q = idx & 7;
            bf16x8 v = (bf16x8)0;
            if (n < MAX_HIST) {
                const int id = ids[b * MAX_HIST + n];
                const float4* p = (const float4*)(items + id * EMBED_DIM + q * 8);
                float4 v0 = p[0], v1 = p[1];
                v[0] = (short)f2bf(v0.x); v[1] = (short)f2bf(v0.y);
                v[2] = (short)f2bf(v0.z); v[3] = (short)f2bf(v0.w);
                v[4] = (short)f2bf(v1.x); v[5] = (short)f2bf(v1.y);
                v[6] = (short)f2bf(v1.z); v[7] = (short)f2bf(v1.w);
            }
            *(bf16x8*)(hist_bf + (size_t)(b * NPAD + n) * EMBED_DIM + q * 8) = v;
            *(bf16x8*)(sh_h + (size_t)n * EMBED_DIM + q * 8) = v;
        }

        const int len = lens[b];
        float s = -INFINITY;
        if (tid < len) {
            const int id = ids[b * MAX_HIST + tid];
            const float* h = items + id * EMBED_DIM;
            float a0 = 0.f, a1 = 0.f;
#pragma unroll
            for (int f = 0; f < EMBED_DIM; f += 2) {
                a0 += user[f] * h[f];
                a1 += user[f + 1] * h[f + 1];
            }
            float a = a0 + a1;
            s = fmaxf(a, LEAKY * a);
        }
        float m = s;
#pragma unroll
        for (int o = 32; o > 0; o >>= 1) m = fmaxf(m, __shfl_xor(m, o, 64));
        if ((tid & 63) == 0) red[tid >> 6] = m;
        __syncthreads();   // also covers sh_h gather writes
        m = fmaxf(fmaxf(red[0], red[1]), fmaxf(red[2], red[3]));

        float e = (tid < len) ? __expf(s - m) : 0.f;
        float t = e;
#pragma unroll
        for (int o = 32; o > 0; o >>= 1) t += __shfl_xor(t, o, 64);
        if ((tid & 63) == 0) red[4 + (tid >> 6)] = t;
        __syncthreads();
        const float sum = red[4] + red[5] + red[6] + red[7];

        if (tid < NPAD) sh_usf[tid] = (tid < len) ? (e / sum) : 0.f;
        __syncthreads();

        // uh[f] = sum_n us[n] * hist[n][f] -- all from LDS (no serial global gather)
        const int f = tid & 63;
        const int part = tid >> 6;
        float uhp = 0.f;
        for (int n = part; n < len; n += 4)
            uhp += sh_usf[n] * bf2f(sh_h[n * EMBED_DIM + f]);
        sh_uh[part][f] = uhp;
        __syncthreads();
        if (tid < EMBED_DIM)
            uh_bf[b * EMBED_DIM + tid] =
                f2bf(sh_uh[0][tid] + sh_uh[1][tid] + sh_uh[2][tid] + sh_uh[3][tid]);
    }
}

// ---------------- Kernel C: MFMA main — 256 items/block, 4 iterations/wave, frag prefetch
__global__ __launch_bounds__(256) void main_kernel(const unsigned short* __restrict__ items_att_bf,
                                                   const unsigned short* __restrict__ wti_bf,
                                                   const float* __restrict__ bdot,
                                                   const unsigned short* __restrict__ hist_bf,
                                                   const unsigned short* __restrict__ uh_bf,
                                                   const int* __restrict__ lens,
                                                   float* __restrict__ out) {
    const int b = blockIdx.y;
    const int tid = threadIdx.x;
    const int lane = tid & 63;
    const int w = tid >> 6;

    __shared__ __align__(16) unsigned short sh_hist[NPAD * EMBED_DIM];  // 26.6 KB, swizzled

    const int len = lens[b];                 // block-uniform
    const int ntiles = (len + 15) >> 4;      // 1..13

    const int c16 = lane & 15;   // item column within 16-group
    const int g = lane >> 4;     // k-chunk / n-subrow group

    // uh fragment (reused by all 4 iterations)
    bf16x8 u0 = *(const bf16x8*)(uh_bf + b * 64 + g * 8);
    bf16x8 u1 = *(const bf16x8*)(uh_bf + b * 64 + 32 + g * 8);

    // stage only the rows we need (XOR-swizzle: row stride 128 B)
    const float4* src = (const float4*)(hist_bf + (size_t)b * NPAD * EMBED_DIM);
    const int nf4 = ntiles * 16 * 8;
    for (int c = tid; c < nf4; c += 256) {
        const int n = c >> 3, q = c & 7;
        float4 v = src[c];
        const int byte = (n * 128 + q * 16) ^ ((n & 7) << 4);
        *(float4*)((char*)sh_hist + byte) = v;
    }
    __syncthreads();
    // NOTE: no __syncthreads below this point (sh_hist is read-only) -> waves may
    // skip iterations / exit independently.

    const char* hbase = (const char*)sh_hist;

#define LDA(T, X0, X1)                                                   \
    {                                                                    \
        const int n_ = (T) * 16 + c16;                                   \
        const int base_ = n_ * 128, sw_ = (n_ & 7) << 4;                 \
        X0 = *(const bf16x8*)(hbase + ((base_ + g * 16) ^ sw_));         \
        X1 = *(const bf16x8*)(hbase + ((base_ + 64 + g * 16) ^ sw_));    \
    }

#define EPI(S, H, Se, Sh, MASKED, NB)                                    \
    {                                                                    \
        float s0 = fminf(fmaxf(S[0], LEAKY * S[0]), ECLAMP);             \
        float s1 = fminf(fmaxf(S[1], LEAKY * S[1]), ECLAMP);             \
        float s2 = fminf(fmaxf(S[2], LEAKY * S[2]), ECLAMP);             \
        float s3 = fminf(fmaxf(S[3], LEAKY * S[3]), ECLAMP);             \
        if (MASKED) {                                                    \
            s0 = ((NB) + 0 < len) ? s0 : -INFINITY;                      \
            s1 = ((NB) + 1 < len) ? s1 : -INFINITY;                      \
            s2 = ((NB) + 2 < len) ? s2 : -INFINITY;                      \
            s3 = ((NB) + 3 < len) ? s3 : -INFINITY;                      \
        }                                                                \
        const float e0 = fexp2(s0), e1 = fexp2(s1);                      \
        const float e2 = fexp2(s2), e3 = fexp2(s3);                      \
        Se += (e0 + e1) + (e2 + e3);                                     \
        Sh = fmaf(e0, H[0], fmaf(e1, H[1], fmaf(e2, H[2], fmaf(e3, H[3], Sh)))); \
    }

    const int wbase = blockIdx.x * 256 + w * 16;    // this wave's first group start

    // current-iteration B-fragments (prefetched across iterations)
    int ild = min(wbase + c16, NUM_ITEMS - 1);      // clamp: garbage stays in dead columns
    bf16x8 itc0 = *(const bf16x8*)(items_att_bf + (size_t)ild * 64 + g * 8);
    bf16x8 itc1 = *(const bf16x8*)(items_att_bf + (size_t)ild * 64 + 32 + g * 8);
    bf16x8 wtc0 = *(const bf16x8*)(wti_bf + (size_t)ild * 64 + g * 8);
    bf16x8 wtc1 = *(const bf16x8*)(wti_bf + (size_t)ild * 64 + 32 + g * 8);

#pragma unroll
    for (int it = 0; it < 4; ++it) {
        const int gstart = wbase + it * 64;
        if (gstart >= NUM_ITEMS) break;             // 16-aligned groups: fully live or dead

        // prefetch next iteration's fragments (latency hides under this iteration)
        bf16x8 nt0, nt1, nw0, nw1;
        if (it < 3) {
            const int inx = min(wbase + (it + 1) * 64 + c16, NUM_ITEMS - 1);
            nt0 = *(const bf16x8*)(items_att_bf + (size_t)inx * 64 + g * 8);
            nt1 = *(const bf16x8*)(items_att_bf + (size_t)inx * 64 + 32 + g * 8);
            nw0 = *(const bf16x8*)(wti_bf + (size_t)inx * 64 + g * 8);
            nw1 = *(const bf16x8*)(wti_bf + (size_t)inx * 64 + 32 + g * 8);
        }

        // user-perspective term via broadcast-A MFMA: all A rows = uh -> every lane's
        // suf[0] = uh . wti[item of this column]
        f32x4 suf = (f32x4)0.f;
        suf = __builtin_amdgcn_mfma_f32_16x16x32_bf16(u0, wtc0, suf, 0, 0, 0);
        suf = __builtin_amdgcn_mfma_f32_16x16x32_bf16(u1, wtc1, suf, 0, 0, 0);
        const float Su = suf[0];

        float Se = 0.f, Sh = 0.f;
        bf16x8 a0, a1;
        LDA(0, a0, a1)

        for (int t = 0; t < ntiles - 1; ++t) {
            f32x4 S = (f32x4)0.f, H = (f32x4)0.f;
            S = __builtin_amdgcn_mfma_f32_16x16x32_bf16(a0, itc0, S, 0, 0, 0);
            S = __builtin_amdgcn_mfma_f32_16x16x32_bf16(a1, itc1, S, 0, 0, 0);
            H = __builtin_amdgcn_mfma_f32_16x16x32_bf16(a0, wtc0, H, 0, 0, 0);
            H = __builtin_amdgcn_mfma_f32_16x16x32_bf16(a1, wtc1, H, 0, 0, 0);
            bf16x8 p0, p1;
            LDA(t + 1, p0, p1)                       // LDS prefetch (t+1 <= ntiles-1)
            EPI(S, H, Se, Sh, 0, 0)
            a0 = p0; a1 = p1;
        }
        {   // final tile, masked
            f32x4 S = (f32x4)0.f, H = (f32x4)0.f;
            S = __builtin_amdgcn_mfma_f32_16x16x32_bf16(a0, itc0, S, 0, 0, 0);
            S = __builtin_amdgcn_mfma_f32_16x16x32_bf16(a1, itc1, S, 0, 0, 0);
            H = __builtin_amdgcn_mfma_f32_16x16x32_bf16(a0, wtc0, H, 0, 0, 0);
            H = __builtin_amdgcn_mfma_f32_16x16x32_bf16(a1, wtc1, H, 0, 0, 0);
            const int nb = (ntiles - 1) * 16 + g * 4;
            EPI(S, H, Se, Sh, 1, nb)
        }

        // fixed-scale combine across the 4 n-groups; clamp bounds Sh ~ 2^126 < FLT_MAX
        Se += __shfl_xor(Se, 16, 64); Se += __shfl_xor(Se, 32, 64);
        Sh += __shfl_xor(Sh, 16, 64); Sh += __shfl_xor(Sh, 32, 64);

        if (g == 0) {
            const int i = gstart + c16;              // < NUM_ITEMS (group fully live)
            out[(size_t)b * NUM_ITEMS + i] =
                (1.0f - W_USER) * (Sh / Se) + W_USER * Su + bdot[i];
        }

        if (it < 3) { itc0 = nt0; itc1 = nt1; wtc0 = nw0; wtc1 = nw1; }
    }
#undef EPI
#undef LDA
}

extern "C" void kernel_launch(void* const* d_in, const int* in_sizes, int n_in,
                              void* d_out, int out_size, void* d_ws, size_t ws_size,
                              hipStream_t stream) {
    const int* ids = (const int*)d_in[0];
    const int* lens = (const int*)d_in[1];
    const float* items = (const float*)d_in[2];
    const float* user = (const float*)d_in[3];
    const float* W = (const float*)d_in[4];
    const float* bias = (const float*)d_in[5];
    float* out = (float*)d_out;

    char* p = (char*)d_ws;
    unsigned short* items_att_bf = (unsigned short*)p; p += (size_t)NUM_ITEMS * EMBED_DIM * 2;
    unsigned short* wti_bf       = (unsigned short*)p; p += (size_t)NUM_ITEMS * EMBED_DIM * 2;
    float* bdot                  = (float*)p;          p += (size_t)NUM_ITEMS * 4;
    unsigned short* hist_bf      = (unsigned short*)p; p += (size_t)BATCH * NPAD * EMBED_DIM * 2;
    unsigned short* uh_bf        = (unsigned short*)p; p += (size_t)BATCH * EMBED_DIM * 2;

    prep_kernel<<<NWTI + BATCH, 256, 0, stream>>>(ids, lens, items, user, W, bias,
                                                  items_att_bf, wti_bf, bdot,
                                                  hist_bf, uh_bf);

    dim3 grid((NUM_ITEMS + 255) / 256, BATCH);
    main_kernel<<<grid, 256, 0, stream>>>(items_att_bf, wti_bf, bdot, hist_bf, uh_bf, lens, out);
}

// Round 8
// 41.106 us; speedup vs baseline: 1.1542x; 1.0844x over previous
//
#include <hip/hip_runtime.h>
#include <hip/hip_bf16.h>
#include <math.h>

#define NUM_ITEMS 10000
#define EMBED_DIM 64
#define MAX_HIST 200
#define NPAD 208          // MAX_HIST padded to multiple of 16
#define BATCH 32
#define LEAKY 0.2f
#define W_USER 0.5f
#define LOG2E 1.4426950408889634f
#define ECLAMP 110.0f     // exp2 ceiling: Sh <= 208*2^110*2^6*4 ~ 2^126 < FLT_MAX
#define NCAST 313         // ceil(10000*64/8 / 256) blocks for the cast branch

typedef short bf16x8 __attribute__((ext_vector_type(8)));
typedef float f32x4 __attribute__((ext_vector_type(4)));

__device__ __forceinline__ unsigned short f2bf(float f) {
    __hip_bfloat16 h = __float2bfloat16(f);
    return __builtin_bit_cast(unsigned short, h);
}

__device__ __forceinline__ float bf2f(unsigned short u) {
    return __builtin_bit_cast(float, (unsigned int)u << 16);
}

__device__ __forceinline__ float fexp2(float x) {
#if __has_builtin(__builtin_amdgcn_exp2f)
    return __builtin_amdgcn_exp2f(x);
#else
    return exp2f(x);
#endif
}

__device__ __forceinline__ bf16x8 cvt8(float4 a, float4 b) {
    bf16x8 v;
    v[0] = (short)f2bf(a.x); v[1] = (short)f2bf(a.y);
    v[2] = (short)f2bf(a.z); v[3] = (short)f2bf(a.w);
    v[4] = (short)f2bf(b.x); v[5] = (short)f2bf(b.y);
    v[6] = (short)f2bf(b.z); v[7] = (short)f2bf(b.w);
    return v;
}

// ---------------- Kernel P (fused prep):
// blocks [0, NCAST):        items_bf = bf16(items)  (pure elementwise cast)
// blocks [NCAST, NCAST+32): hist gather -> histL_bf (hist*log2e); histW_bf = hist@W^T (MFMA);
//                           user softmax -> v_bf[b] = W_USER*(uh@W^T) + bias
__global__ __launch_bounds__(256) void prep_kernel(const int* __restrict__ ids,
                                                   const int* __restrict__ lens,
                                                   const float* __restrict__ items,
                                                   const float* __restrict__ user,
                                                   const float* __restrict__ W,
                                                   const float* __restrict__ bias,
                                                   unsigned short* __restrict__ items_bf,
                                                   unsigned short* __restrict__ histL_bf,
                                                   unsigned short* __restrict__ histW_bf,
                                                   unsigned short* __restrict__ v_bf) {
    const int tid = threadIdx.x;

    if (blockIdx.x < NCAST) {
        // ---- cast branch: 8 floats per thread ----
        const int c = blockIdx.x * 256 + tid;
        if (c < NUM_ITEMS * EMBED_DIM / 8) {
            const float4* p = (const float4*)items + 2 * c;
            *(bf16x8*)(items_bf + (size_t)c * 8) = cvt8(p[0], p[1]);
        }
        return;
    }

    // ---- hist branch ----
    const int b = blockIdx.x - NCAST;
    __shared__ __align__(16) unsigned short sh_h[NPAD * EMBED_DIM];  // unscaled bf16, linear
    __shared__ float red[8];
    __shared__ float sh_usf[NPAD];
    __shared__ float sh_uh[4][EMBED_DIM];
    __shared__ float sh_uhf[EMBED_DIM];

    const int len = lens[b];
    const int ntiles = (len + 15) >> 4;

    // gather: sh_h = bf16(hist), global histL = bf16(hist * log2e)
    for (int idx = tid; idx < NPAD * 8; idx += 256) {
        const int n = idx >> 3;
        bf16x8 vu = (bf16x8)0, vs = (bf16x8)0;
        if (n < MAX_HIST) {
            const int id = ids[b * MAX_HIST + n];
            const float4* p = (const float4*)(items + (size_t)id * EMBED_DIM + (idx & 7) * 8);
            float4 v0 = p[0], v1 = p[1];
            vu = cvt8(v0, v1);
            float4 s0 = make_float4(v0.x * LOG2E, v0.y * LOG2E, v0.z * LOG2E, v0.w * LOG2E);
            float4 s1 = make_float4(v1.x * LOG2E, v1.y * LOG2E, v1.z * LOG2E, v1.w * LOG2E);
            vs = cvt8(s0, s1);
        }
        *(bf16x8*)(sh_h + (size_t)idx * 8) = vu;
        *(bf16x8*)(histL_bf + (size_t)b * NPAD * EMBED_DIM + (size_t)idx * 8) = vs;
    }
    __syncthreads();

    // histW = hist @ W^T via MFMA. Wave w owns f-tile w (f = w*16 + c16).
    {
        const int lane = tid & 63;
        const int w = tid >> 6;
        const int c16 = lane & 15;
        const int g = lane >> 4;
        const int f = w * 16 + c16;
        const float* wrow = W + (size_t)f * EMBED_DIM;
        // B[k=g', col=f] = W[f, g']: frag kk=0 -> k=8g..8g+7, kk=1 -> k=32+8g..
        float4 wa = *(const float4*)(wrow + g * 8);
        float4 wb = *(const float4*)(wrow + g * 8 + 4);
        float4 wc = *(const float4*)(wrow + 32 + g * 8);
        float4 wd = *(const float4*)(wrow + 32 + g * 8 + 4);
        bf16x8 b0 = cvt8(wa, wb), b1 = cvt8(wc, wd);

        for (int t = 0; t < ntiles; ++t) {
            const int n = t * 16 + c16;
            bf16x8 a0 = *(const bf16x8*)(sh_h + n * EMBED_DIM + g * 8);
            bf16x8 a1 = *(const bf16x8*)(sh_h + n * EMBED_DIM + 32 + g * 8);
            f32x4 D = (f32x4)0.f;
            D = __builtin_amdgcn_mfma_f32_16x16x32_bf16(a0, b0, D, 0, 0, 0);
            D = __builtin_amdgcn_mfma_f32_16x16x32_bf16(a1, b1, D, 0, 0, 0);
#pragma unroll
            for (int j = 0; j < 4; ++j) {
                const int nr = t * 16 + g * 4 + j;   // C/D: col=c16(f), row=4g+j
                histW_bf[(size_t)(b * NPAD + nr) * EMBED_DIM + f] = f2bf(D[j]);
            }
        }
    }

    // user-perspective softmax (f32, global reads)
    float s = -INFINITY;
    if (tid < len) {
        const int id = ids[b * MAX_HIST + tid];
        const float* h = items + (size_t)id * EMBED_DIM;
        float a0 = 0.f, a1 = 0.f;
#pragma unroll
        for (int fi = 0; fi < EMBED_DIM; fi += 2) {
            a0 += user[fi] * h[fi];
            a1 += user[fi + 1] * h[fi + 1];
        }
        float a = a0 + a1;
        s = fmaxf(a, LEAKY * a);
    }
    float m = s;
#pragma unroll
    for (int o = 32; o > 0; o >>= 1) m = fmaxf(m, __shfl_xor(m, o, 64));
    if ((tid & 63) == 0) red[tid >> 6] = m;
    __syncthreads();
    m = fmaxf(fmaxf(red[0], red[1]), fmaxf(red[2], red[3]));

    float e = (tid < len) ? __expf(s - m) : 0.f;
    float t = e;
#pragma unroll
    for (int o = 32; o > 0; o >>= 1) t += __shfl_xor(t, o, 64);
    if ((tid & 63) == 0) red[4 + (tid >> 6)] = t;
    __syncthreads();
    const float sum = red[4] + red[5] + red[6] + red[7];

    if (tid < NPAD) sh_usf[tid] = (tid < len) ? (e / sum) : 0.f;
    __syncthreads();

    // uh[f] = sum_n us[n] * hist[n][f]  (from LDS)
    {
        const int f = tid & 63;
        const int part = tid >> 6;
        float uhp = 0.f;
        for (int n = part; n < len; n += 4)
            uhp += sh_usf[n] * bf2f(sh_h[n * EMBED_DIM + f]);
        sh_uh[part][f] = uhp;
    }
    __syncthreads();
    if (tid < EMBED_DIM)
        sh_uhf[tid] = sh_uh[0][tid] + sh_uh[1][tid] + sh_uh[2][tid] + sh_uh[3][tid];
    __syncthreads();

    // v[f] = W_USER * sum_g uh[g]*W[f,g] + bias[f]
    if (tid < EMBED_DIM) {
        const float* wrow = W + (size_t)tid * EMBED_DIM;
        float acc = 0.f;
#pragma unroll 8
        for (int g2 = 0; g2 < EMBED_DIM; ++g2) acc += sh_uhf[g2] * wrow[g2];
        v_bf[b * EMBED_DIM + tid] = f2bf(W_USER * acc + bias[tid]);
    }
}

// ---------------- Kernel C: MFMA main — 256 items/block, single B matrix (items_bf)
__global__ __launch_bounds__(256) void main_kernel(const unsigned short* __restrict__ items_bf,
                                                   const unsigned short* __restrict__ histL_bf,
                                                   const unsigned short* __restrict__ histW_bf,
                                                   const unsigned short* __restrict__ v_bf,
                                                   const int* __restrict__ lens,
                                                   float* __restrict__ out) {
    const int b = blockIdx.y;
    const int tid = threadIdx.x;
    const int lane = tid & 63;
    const int w = tid >> 6;

    __shared__ __align__(16) unsigned short sh_L[NPAD * EMBED_DIM];  // hist*log2e, swizzled
    __shared__ __align__(16) unsigned short sh_W[NPAD * EMBED_DIM];  // hist@W^T, swizzled

    const int len = lens[b];                 // block-uniform
    const int ntiles = (len + 15) >> 4;      // 1..13

    const int c16 = lane & 15;   // item column within 16-group
    const int g = lane >> 4;     // k-chunk / n-subrow group

    // v fragment (broadcast-A; reused by all iterations)
    bf16x8 v0 = *(const bf16x8*)(v_bf + b * 64 + g * 8);
    bf16x8 v1 = *(const bf16x8*)(v_bf + b * 64 + 32 + g * 8);

    // stage histL and histW tiles (XOR-swizzle: row stride 128 B)
    const int nf4 = ntiles * 16 * 8;
    {
        const float4* srcL = (const float4*)(histL_bf + (size_t)b * NPAD * EMBED_DIM);
        const float4* srcW = (const float4*)(histW_bf + (size_t)b * NPAD * EMBED_DIM);
        for (int c = tid; c < nf4; c += 256) {
            const int n = c >> 3, q = c & 7;
            const int byte = (n * 128 + q * 16) ^ ((n & 7) << 4);
            *(float4*)((char*)sh_L + byte) = srcL[c];
            *(float4*)((char*)sh_W + byte) = srcW[c];
        }
    }
    __syncthreads();
    // sh_L/sh_W read-only below: waves proceed independently.

#define LDA(BASE, T, X0, X1)                                                  \
    {                                                                         \
        const int n_ = (T) * 16 + c16;                                        \
        const int base_ = n_ * 128, sw_ = (n_ & 7) << 4;                      \
        X0 = *(const bf16x8*)((const char*)(BASE) + ((base_ + g * 16) ^ sw_));\
        X1 = *(const bf16x8*)((const char*)(BASE) + ((base_ + 64 + g * 16) ^ sw_)); \
    }

#define EPI(S, H, Se, Sh, MASKED, NB)                                    \
    {                                                                    \
        float s0 = fminf(fmaxf(S[0], LEAKY * S[0]), ECLAMP);             \
        float s1 = fminf(fmaxf(S[1], LEAKY * S[1]), ECLAMP);             \
        float s2 = fminf(fmaxf(S[2], LEAKY * S[2]), ECLAMP);             \
        float s3 = fminf(fmaxf(S[3], LEAKY * S[3]), ECLAMP);             \
        if (MASKED) {                                                    \
            s0 = ((NB) + 0 < len) ? s0 : -INFINITY;                      \
            s1 = ((NB) + 1 < len) ? s1 : -INFINITY;                      \
            s2 = ((NB) + 2 < len) ? s2 : -INFINITY;                      \
            s3 = ((NB) + 3 < len) ? s3 : -INFINITY;                      \
        }                                                                \
        const float e0 = fexp2(s0), e1 = fexp2(s1);                      \
        const float e2 = fexp2(s2), e3 = fexp2(s3);                      \
        Se += (e0 + e1) + (e2 + e3);                                     \
        Sh = fmaf(e0, H[0], fmaf(e1, H[1], fmaf(e2, H[2], fmaf(e3, H[3], Sh)))); \
    }

    const int wbase = blockIdx.x * 256 + w * 16;

    // current-iteration B-fragments (prefetched across iterations)
    int ild = min(wbase + c16, NUM_ITEMS - 1);
    bf16x8 itc0 = *(const bf16x8*)(items_bf + (size_t)ild * 64 + g * 8);
    bf16x8 itc1 = *(const bf16x8*)(items_bf + (size_t)ild * 64 + 32 + g * 8);

#pragma unroll
    for (int it = 0; it < 4; ++it) {
        const int gstart = wbase + it * 64;
        if (gstart >= NUM_ITEMS) break;              // 16-aligned: groups fully live or dead

        bf16x8 nt0, nt1;
        if (it < 3) {
            const int inx = min(wbase + (it + 1) * 64 + c16, NUM_ITEMS - 1);
            nt0 = *(const bf16x8*)(items_bf + (size_t)inx * 64 + g * 8);
            nt1 = *(const bf16x8*)(items_bf + (size_t)inx * 64 + 32 + g * 8);
        }

        // combined user+bias term: Sv = v[b] . items[i]  (broadcast-A MFMA)
        f32x4 suf = (f32x4)0.f;
        suf = __builtin_amdgcn_mfma_f32_16x16x32_bf16(v0, itc0, suf, 0, 0, 0);
        suf = __builtin_amdgcn_mfma_f32_16x16x32_bf16(v1, itc1, suf, 0, 0, 0);
        const float Sv = suf[0];

        float Se = 0.f, Sh = 0.f;
        bf16x8 aL0, aL1, aW0, aW1;
        LDA(sh_L, 0, aL0, aL1)
        LDA(sh_W, 0, aW0, aW1)

        for (int t = 0; t < ntiles - 1; ++t) {
            f32x4 S = (f32x4)0.f, H = (f32x4)0.f;
            S = __builtin_amdgcn_mfma_f32_16x16x32_bf16(aL0, itc0, S, 0, 0, 0);
            S = __builtin_amdgcn_mfma_f32_16x16x32_bf16(aL1, itc1, S, 0, 0, 0);
            H = __builtin_amdgcn_mfma_f32_16x16x32_bf16(aW0, itc0, H, 0, 0, 0);
            H = __builtin_amdgcn_mfma_f32_16x16x32_bf16(aW1, itc1, H, 0, 0, 0);
            bf16x8 pL0, pL1, pW0, pW1;
            LDA(sh_L, t + 1, pL0, pL1)               // prefetch next tile
            LDA(sh_W, t + 1, pW0, pW1)
            EPI(S, H, Se, Sh, 0, 0)
            aL0 = pL0; aL1 = pL1; aW0 = pW0; aW1 = pW1;
        }
        {   // final tile, masked
            f32x4 S = (f32x4)0.f, H = (f32x4)0.f;
            S = __builtin_amdgcn_mfma_f32_16x16x32_bf16(aL0, itc0, S, 0, 0, 0);
            S = __builtin_amdgcn_mfma_f32_16x16x32_bf16(aL1, itc1, S, 0, 0, 0);
            H = __builtin_amdgcn_mfma_f32_16x16x32_bf16(aW0, itc0, H, 0, 0, 0);
            H = __builtin_amdgcn_mfma_f32_16x16x32_bf16(aW1, itc1, H, 0, 0, 0);
            const int nb = (ntiles - 1) * 16 + g * 4;
            EPI(S, H, Se, Sh, 1, nb)
        }

        Se += __shfl_xor(Se, 16, 64); Se += __shfl_xor(Se, 32, 64);
        Sh += __shfl_xor(Sh, 16, 64); Sh += __shfl_xor(Sh, 32, 64);

        if (g == 0) {
            const int i = gstart + c16;
            out[(size_t)b * NUM_ITEMS + i] = (1.0f - W_USER) * (Sh / Se) + Sv;
        }

        if (it < 3) { itc0 = nt0; itc1 = nt1; }
    }
#undef EPI
#undef LDA
}

extern "C" void kernel_launch(void* const* d_in, const int* in_sizes, int n_in,
                              void* d_out, int out_size, void* d_ws, size_t ws_size,
                              hipStream_t stream) {
    const int* ids = (const int*)d_in[0];
    const int* lens = (const int*)d_in[1];
    const float* items = (const float*)d_in[2];
    const float* user = (const float*)d_in[3];
    const float* W = (const float*)d_in[4];
    const float* bias = (const float*)d_in[5];
    float* out = (float*)d_out;

    char* p = (char*)d_ws;
    unsigned short* items_bf = (unsigned short*)p; p += (size_t)NUM_ITEMS * EMBED_DIM * 2;
    unsigned short* histL_bf = (unsigned short*)p; p += (size_t)BATCH * NPAD * EMBED_DIM * 2;
    unsigned short* histW_bf = (unsigned short*)p; p += (size_t)BATCH * NPAD * EMBED_DIM * 2;
    unsigned short* v_bf     = (unsigned short*)p; p += (size_t)BATCH * EMBED_DIM * 2;

    prep_kernel<<<NCAST + BATCH, 256, 0, stream>>>(ids, lens, items, user, W, bias,
                                                   items_bf, histL_bf, histW_bf, v_bf);

    dim3 grid((NUM_ITEMS + 255) / 256, BATCH);
    main_kernel<<<grid, 256, 0, stream>>>(items_bf, histL_bf, histW_bf, v_bf, lens, out);
}